// Round 6
// baseline (174.942 us; speedup 1.0000x reference)
//
#include <hip/hip_runtime.h>

// Gated delta rule recurrence S_t = S_{t-1} @ A_t + B_t, outputs all S_t.
// T=128, B*H=64 chains, D=64. Two-level chunked scan, NC=16 chunks of CH=8.
//   K1 (fold): chunk summaries (PA,PB)           [1024 blocks x 7 steps]
//   K2 (scan): over 16 summaries -> chunk-end states into out [64 blocks]
//   K3 (scan): in-chunk recurrence -> remaining states        [1024 blocks]
// Split-bf16 MFMA (hi/lo, 3 products). Accumulator in registers; C/D->B-operand
// transform via ds_bpermute. Only A is LDS-staged (double-buffered).
// r6 CHANGE (anti-convoy): prefetch registers are now pipelined -
//   * A-prefetch double-buffered (bufA0/bufA1): issue elem j+4 into buf[j&1]
//     right after staging consumes it -> two A bursts always in flight.
//   * B-prefetch reissued at step TOP immediately after consumption.
// So global loads are issued before compute and never wait on a full drain;
// memory stays busy during the MFMA phase instead of idling (convoy-break).
// Static buffer names via 2-unrolled loop (avoids scratch demotion).

constexpr int kT = 128;
constexpr int kBH = 64;
constexpr int kD = 64;
constexpr int kTile = kD * kD;
constexpr int kNC = 16;
constexpr int kCH = 8;

typedef __attribute__((ext_vector_type(8))) short short8;
typedef __attribute__((ext_vector_type(4))) float f32x4;
using u32 = unsigned int;

union U8 { u32 u[4]; short8 s; };

// Barrier that does NOT drain outstanding global loads (LDS ops only).
__device__ __forceinline__ void softBarrier() {
  asm volatile("s_waitcnt lgkmcnt(0)" ::: "memory");
  __builtin_amdgcn_s_barrier();
}

// XOR swizzle (ushort units) for [64][64] bf16 planes: byte ^= (row&7)<<4.
__device__ __forceinline__ int swzi(int r, int c) { return (r * 64 + c) ^ ((r & 7) << 3); }

__device__ __forceinline__ f32x4 mfma16(short8 a, short8 b, f32x4 c) {
  return __builtin_amdgcn_mfma_f32_16x16x32_bf16(a, b, c, 0, 0, 0);
}

// split 2 floats into packed hi/lo bf16 pairs (1 v_cvt_pk each + exact residual)
__device__ __forceinline__ void pk_split(float a, float b, u32& h, u32& l) {
  u32 hu;
  asm("v_cvt_pk_bf16_f32 %0, %1, %2" : "=v"(hu) : "v"(a), "v"(b));
  const float ra = a - __uint_as_float(hu << 16);
  const float rb = b - __uint_as_float(hu & 0xffff0000u);
  u32 lu;
  asm("v_cvt_pk_bf16_f32 %0, %1, %2" : "=v"(lu) : "v"(ra), "v"(rb));
  h = hu;
  l = lu;
}

// Build one K=32 B-operand fragment from two C/D tiles (X = tile 2ks, Y = 2ks+1).
__device__ __forceinline__ short8 gather_frag(u32 p01, u32 p23, u32 q01, u32 q23,
                                              int ad0, int ad1, bool lowh) {
  U8 r;
  int x, y;
  x = __builtin_amdgcn_ds_bpermute(ad0, (int)p01);
  y = __builtin_amdgcn_ds_bpermute(ad0, (int)q01);
  r.u[0] = (u32)(lowh ? x : y);
  x = __builtin_amdgcn_ds_bpermute(ad0, (int)p23);
  y = __builtin_amdgcn_ds_bpermute(ad0, (int)q23);
  r.u[1] = (u32)(lowh ? x : y);
  x = __builtin_amdgcn_ds_bpermute(ad1, (int)p01);
  y = __builtin_amdgcn_ds_bpermute(ad1, (int)q01);
  r.u[2] = (u32)(lowh ? x : y);
  x = __builtin_amdgcn_ds_bpermute(ad1, (int)p23);
  y = __builtin_amdgcn_ds_bpermute(ad1, (int)q23);
  r.u[3] = (u32)(lowh ? x : y);
  return r.s;
}

__device__ __forceinline__ void load_pfA(float* pfA, const float* At, int lane, int w) {
#pragma unroll
  for (int kk = 0; kk < 16; ++kk) pfA[kk] = At[(w * 16 + kk) * 64 + lane];
}
__device__ __forceinline__ void load_pfB(f32x4* pfB, const float* Bt, int rowbase, int q) {
#pragma unroll
  for (int cm = 0; cm < 4; ++cm)
    pfB[cm] = *reinterpret_cast<const f32x4*>(Bt + rowbase + cm * 16 + q * 4);
}

// stage A^T into LDS plane pair: thread (w,lane) writes sA[row=lane][cols w*16..+15]
__device__ __forceinline__ void stage_A(unsigned short* Ah, unsigned short* Al,
                                        const float* pfA, int lane, int w) {
#pragma unroll
  for (int s = 0; s < 2; ++s) {
    U8 h, l;
#pragma unroll
    for (int p = 0; p < 4; ++p) {
      u32 hu, lu;
      pk_split(pfA[s * 8 + 2 * p], pfA[s * 8 + 2 * p + 1], hu, lu);
      h.u[p] = hu;
      l.u[p] = lu;
    }
    const int idx = swzi(lane, w * 16 + s * 8);
    *reinterpret_cast<short8*>(&Ah[idx]) = h.s;
    *reinterpret_cast<short8*>(&Al[idx]) = l.s;
  }
}

// ---------------- fold: (pa,pb) <- fold of nElem (A,B) elements ----------------
__global__ __launch_bounds__(256, 4) void gdr_fold(
    const float* __restrict__ srcA, const float* __restrict__ srcB,
    float* __restrict__ dstA, float* __restrict__ dstB,
    int perChain, long chainBase, long idxBase, long elemStride, int nElem) {
  __shared__ unsigned short sAh[2][4096], sAl[2][4096];

  const int tid = threadIdx.x;
  const int lane = tid & 63, w = tid >> 6;
  const int q = lane >> 4, l15 = lane & 15;
  const int bh = blockIdx.x / perChain, id = blockIdx.x % perChain;
  const long e0 = (long)bh * chainBase + (long)id * idxBase;
  const int rowbase = (w * 16 + l15) * 64;
  const int ad0 = (l15 + ((lane >> 4) & 1) * 32) * 4;
  const int ad1 = ad0 + 64;
  const bool lowh = lane < 32;
  const int nS = nElem - 1;  // steps applying elements 1..nElem-1
  const int eMax = nElem - 1;

  auto Aat = [&](int e) {
    e = e < eMax ? e : eMax;
    return srcA + (size_t)(e0 + (long)e * elemStride) * kTile;
  };
  auto Bat = [&](int e) {
    e = e < eMax ? e : eMax;
    return srcB + (size_t)(e0 + (long)e * elemStride) * kTile;
  };

  f32x4 apa[4], apb[4];
  {
    const float* At = Aat(0);
    const float* Bt = Bat(0);
#pragma unroll
    for (int cm = 0; cm < 4; ++cm) {
      apa[cm] = *reinterpret_cast<const f32x4*>(At + rowbase + cm * 16 + q * 4);
      apb[cm] = *reinterpret_cast<const f32x4*>(Bt + rowbase + cm * 16 + q * 4);
    }
  }

  float bufA0[16], bufA1[16];
  f32x4 bufB[4];
  load_pfA(bufA0, Aat(1), lane, w);
  stage_A(sAh[0], sAl[0], bufA0, lane, w);
  load_pfA(bufA0, Aat(2), lane, w);   // consumed at step 0
  load_pfA(bufA1, Aat(3), lane, w);   // consumed at step 1
  load_pfB(bufB, Bat(1), rowbase, q); // consumed at step 0
  softBarrier();

  auto step = [&](int j, int cur, float* bufAc) {
    const bool more = (j + 1 < nS);
    f32x4 npa[4], npb[4];
#pragma unroll
    for (int cm = 0; cm < 4; ++cm) {
      npa[cm] = (f32x4){0.f, 0.f, 0.f, 0.f};
      npb[cm] = bufB[cm];  // consume B(elem j+1)
    }
    if (more) load_pfB(bufB, Bat(j + 2), rowbase, q);  // reissue immediately
    if (more) {
      stage_A(sAh[cur ^ 1], sAl[cur ^ 1], bufAc, lane, w);  // consume A(elem j+2)
      load_pfA(bufAc, Aat(j + 4), lane, w);                 // reissue (2-step slack)
    }
#pragma unroll
    for (int ks = 0; ks < 2; ++ks) {
      u32 pa01h, pa01l, pa23h, pa23l, qa01h, qa01l, qa23h, qa23l;
      u32 pb01h, pb01l, pb23h, pb23l, qb01h, qb01l, qb23h, qb23l;
      pk_split(apa[2 * ks][0], apa[2 * ks][1], pa01h, pa01l);
      pk_split(apa[2 * ks][2], apa[2 * ks][3], pa23h, pa23l);
      pk_split(apa[2 * ks + 1][0], apa[2 * ks + 1][1], qa01h, qa01l);
      pk_split(apa[2 * ks + 1][2], apa[2 * ks + 1][3], qa23h, qa23l);
      pk_split(apb[2 * ks][0], apb[2 * ks][1], pb01h, pb01l);
      pk_split(apb[2 * ks][2], apb[2 * ks][3], pb23h, pb23l);
      pk_split(apb[2 * ks + 1][0], apb[2 * ks + 1][1], qb01h, qb01l);
      pk_split(apb[2 * ks + 1][2], apb[2 * ks + 1][3], qb23h, qb23l);
      const short8 bah = gather_frag(pa01h, pa23h, qa01h, qa23h, ad0, ad1, lowh);
      const short8 bal = gather_frag(pa01l, pa23l, qa01l, qa23l, ad0, ad1, lowh);
      const short8 bbh = gather_frag(pb01h, pb23h, qb01h, qb23h, ad0, ad1, lowh);
      const short8 bbl = gather_frag(pb01l, pb23l, qb01l, qb23l, ad0, ad1, lowh);
#pragma unroll
      for (int cm = 0; cm < 4; ++cm) {
        const int ai = swzi(cm * 16 + l15, ks * 32 + q * 8);
        const short8 ah = *reinterpret_cast<const short8*>(&sAh[cur][ai]);
        const short8 al = *reinterpret_cast<const short8*>(&sAl[cur][ai]);
        npa[cm] = mfma16(ah, bah, npa[cm]);
        npa[cm] = mfma16(ah, bal, npa[cm]);
        npa[cm] = mfma16(al, bah, npa[cm]);
        npb[cm] = mfma16(ah, bbh, npb[cm]);
        npb[cm] = mfma16(ah, bbl, npb[cm]);
        npb[cm] = mfma16(al, bbh, npb[cm]);
      }
    }
#pragma unroll
    for (int cm = 0; cm < 4; ++cm) { apa[cm] = npa[cm]; apb[cm] = npb[cm]; }
    if (more) softBarrier();
  };

  int j = 0;
  while (true) {
    step(j, 0, bufA0);
    if (++j >= nS) break;
    step(j, 1, bufA1);
    if (++j >= nS) break;
  }

  float* pao = dstA + (size_t)blockIdx.x * kTile;
  float* pbo = dstB + (size_t)blockIdx.x * kTile;
#pragma unroll
  for (int cm = 0; cm < 4; ++cm) {
    *reinterpret_cast<f32x4*>(pao + rowbase + cm * 16 + q * 4) = apa[cm];
    *reinterpret_cast<f32x4*>(pbo + rowbase + cm * 16 + q * 4) = apb[cm];
  }
}

// ---------------- scan: apply nSteps elements, write states into out ----------------
__global__ __launch_bounds__(256, 4) void gdr_scan(
    const float* __restrict__ srcA, const float* __restrict__ srcB,
    const float* __restrict__ S0, float* __restrict__ out,
    int perChain, long chainBase, long idxBase, long elemStride,
    int nSteps, int tbMul, int tStep) {
  __shared__ unsigned short sAh[2][4096], sAl[2][4096];

  const int tid = threadIdx.x;
  const int lane = tid & 63, w = tid >> 6;
  const int q = lane >> 4, l15 = lane & 15;
  const int bh = blockIdx.x / perChain, id = blockIdx.x % perChain;
  const long e0 = (long)bh * chainBase + (long)id * idxBase;
  const int tBase = id * tbMul;
  const int rowbase = (w * 16 + l15) * 64;
  const int ad0 = (l15 + ((lane >> 4) & 1) * 32) * 4;
  const int ad1 = ad0 + 64;
  const bool lowh = lane < 32;
  const int eMax = nSteps - 1;

  auto Aat = [&](int e) {
    e = e < eMax ? e : eMax;
    return srcA + (size_t)(e0 + (long)e * elemStride) * kTile;
  };
  auto Bat = [&](int e) {
    e = e < eMax ? e : eMax;
    return srcB + (size_t)(e0 + (long)e * elemStride) * kTile;
  };

  f32x4 acc[4];
  {
    const float* Sb = (tBase == 0) ? (S0 + (size_t)bh * kTile)
                                   : (out + ((size_t)(tBase - 1) * kBH + bh) * kTile);
#pragma unroll
    for (int cm = 0; cm < 4; ++cm)
      acc[cm] = *reinterpret_cast<const f32x4*>(Sb + rowbase + cm * 16 + q * 4);
  }

  float bufA0[16], bufA1[16];
  f32x4 bufB[4];
  load_pfA(bufA0, Aat(0), lane, w);
  stage_A(sAh[0], sAl[0], bufA0, lane, w);
  load_pfA(bufA0, Aat(1), lane, w);   // consumed at step 0
  load_pfA(bufA1, Aat(2), lane, w);   // consumed at step 1
  load_pfB(bufB, Bat(0), rowbase, q); // consumed at step 0
  softBarrier();

  auto step = [&](int i, int cur, float* bufAc) {
    const bool more = (i + 1 < nSteps);
    f32x4 nacc[4];
#pragma unroll
    for (int cm = 0; cm < 4; ++cm) nacc[cm] = bufB[cm];  // consume B(elem i)
    if (more) load_pfB(bufB, Bat(i + 1), rowbase, q);    // reissue immediately
    if (more) {
      stage_A(sAh[cur ^ 1], sAl[cur ^ 1], bufAc, lane, w);  // consume A(elem i+1)
      load_pfA(bufAc, Aat(i + 3), lane, w);                 // reissue (2-step slack)
    }
#pragma unroll
    for (int ks = 0; ks < 2; ++ks) {
      u32 p01h, p01l, p23h, p23l, q01h, q01l, q23h, q23l;
      pk_split(acc[2 * ks][0], acc[2 * ks][1], p01h, p01l);
      pk_split(acc[2 * ks][2], acc[2 * ks][3], p23h, p23l);
      pk_split(acc[2 * ks + 1][0], acc[2 * ks + 1][1], q01h, q01l);
      pk_split(acc[2 * ks + 1][2], acc[2 * ks + 1][3], q23h, q23l);
      const short8 bfh = gather_frag(p01h, p23h, q01h, q23h, ad0, ad1, lowh);
      const short8 bfl = gather_frag(p01l, p23l, q01l, q23l, ad0, ad1, lowh);
#pragma unroll
      for (int cm = 0; cm < 4; ++cm) {
        const int ai = swzi(cm * 16 + l15, ks * 32 + q * 8);
        const short8 ah = *reinterpret_cast<const short8*>(&sAh[cur][ai]);
        const short8 al = *reinterpret_cast<const short8*>(&sAl[cur][ai]);
        nacc[cm] = mfma16(ah, bfh, nacc[cm]);
        nacc[cm] = mfma16(ah, bfl, nacc[cm]);
        nacc[cm] = mfma16(al, bfh, nacc[cm]);
      }
    }
    const int t = tBase + (i + 1) * tStep - 1;
    float* o = out + ((size_t)t * kBH + bh) * kTile;
#pragma unroll
    for (int cm = 0; cm < 4; ++cm) {
      *reinterpret_cast<f32x4*>(o + rowbase + cm * 16 + q * 4) = nacc[cm];
      acc[cm] = nacc[cm];
    }
    if (more) softBarrier();
  };

  int i = 0;
  while (true) {
    step(i, 0, bufA0);
    if (++i >= nSteps) break;
    step(i, 1, bufA1);
    if (++i >= nSteps) break;
  }
}

extern "C" void kernel_launch(void* const* d_in, const int* in_sizes, int n_in,
                              void* d_out, int out_size, void* d_ws, size_t ws_size,
                              hipStream_t stream) {
  const float* A  = (const float*)d_in[0];
  const float* Bm = (const float*)d_in[1];
  const float* S0 = (const float*)d_in[2];
  float* out = (float*)d_out;

  // workspace: PA[64*16], PB[64*16] tiles of 16 KB = 32 MB
  float* PA = (float*)d_ws;
  float* PB = PA + (size_t)kBH * kNC * kTile;

  // K1: chunk summaries. elements (ck*8+i)*64+bh, i=0..7
  gdr_fold<<<dim3(kBH * kNC), dim3(256), 0, stream>>>(
      A, Bm, PA, PB, kNC, 1L, (long)kCH * kBH, (long)kBH, kCH);
  // K2: scan 16 summaries (tiles bh*16+i); writes t = (i+1)*8-1 (7,15,...,127)
  gdr_scan<<<dim3(kBH), dim3(256), 0, stream>>>(
      PA, PB, S0, out, 1, (long)kNC, 0L, 1L, kNC, 0, kCH);
  // K3: in-chunk recurrence; elements (ck*8+i)*64+bh, start out[ck*8-1]/S0,
  //     writes t = ck*8+i for i=0..6
  gdr_scan<<<dim3(kBH * kNC), dim3(256), 0, stream>>>(
      A, Bm, S0, out, kNC, 1L, (long)kCH * kBH, (long)kBH, kCH - 1, kCH, 1);
}